// Round 14
// baseline (186.253 us; speedup 1.0000x reference)
//
#include <hip/hip_runtime.h>
#include <math.h>

#define NE 256
#define HD 4096
#define TOPKG 4
#define TOPK 8

#define BM 128
#define BN 128
#define BK 32
#define NKB 128  // kb across full K

typedef __attribute__((ext_vector_type(8))) short short8;
typedef __attribute__((ext_vector_type(4))) float f32x4;

#define MFMA __builtin_amdgcn_mfma_f32_16x16x32_bf16

// In-row XOR swizzle (involution): byte bits[5:4] ^= addr bits[8:7].
// Verified conflict-free (R3-R13: SQ_LDS_BANK_CONFLICT == 0). A-side LDS only.
__device__ __forceinline__ unsigned swz(unsigned a) {
  return a ^ (((a >> 7) & 3u) << 4);
}

// Round-to-nearest-even bf16.
__device__ __forceinline__ unsigned short rneb(float x) {
  unsigned u = __float_as_uint(x);
  return (unsigned short)((u + 0x7fffu + ((u >> 16) & 1u)) >> 16);
}
// 2-way ROUNDED split: x = h + m + rho, |rho| <~ 2^-18|x| (R8-R13-proven numerics).
__device__ __forceinline__ void split2(float x, unsigned short& h, unsigned short& m) {
  h = rneb(x);
  float r = x - __uint_as_float(((unsigned)h) << 16);  // exact
  m = rneb(r);
}

// ---------------- W[e][k] -> frag-linear splits (R12-proven layout) ----------------
// [kb][s][cg=e>>4][kq=k>>3][er=e&15][8 bf16] shorts: lane l's B-frag for (cg, kq=l>>4)
// = one coalesced global_load_dwordx4 at base + l*16B, straight from L2.
__global__ void wsplit_kernel(const float* __restrict__ W, unsigned short* __restrict__ W2) {
  const int kb = blockIdx.x >> 1;
  const int e = (blockIdx.x & 1) * 128 + (threadIdx.x >> 1);
  const int seg = (threadIdx.x & 1);  // k half
  const float* src = W + (size_t)e * HD + kb * BK + seg * 16;
  float4 x0 = *(const float4*)(src + 0);
  float4 x1 = *(const float4*)(src + 4);
  float4 x2 = *(const float4*)(src + 8);
  float4 x3 = *(const float4*)(src + 12);
  float xv[16] = {x0.x, x0.y, x0.z, x0.w, x1.x, x1.y, x1.z, x1.w,
                  x2.x, x2.y, x2.z, x2.w, x3.x, x3.y, x3.z, x3.w};
  short8 hv[2], mv[2];
#pragma unroll
  for (int jh = 0; jh < 2; ++jh)
#pragma unroll
    for (int j = 0; j < 8; ++j) {
      unsigned short h, m;
      split2(xv[jh * 8 + j], h, m);
      hv[jh][j] = (short)h; mv[jh][j] = (short)m;
    }
  const int cg = e >> 4, er = e & 15;
  unsigned short* base = W2 + (size_t)kb * 16384 + cg * 512 + er * 8;
#pragma unroll
  for (int jh = 0; jh < 2; ++jh) {
    int kq = seg * 2 + jh;
    *(short8*)(base + 0 * 8192 + kq * 128) = hv[jh];
    *(short8*)(base + 1 * 8192 + kq * 128) = mv[jh];
  }
}

// ---------------- split-K logits: R12 kernel, grid-doubled for occupancy ----------------
// 256 thr = 4 waves (2m x 2n), wave tile 64x64, block 128x128. 4 chains {ah,am}x{bh,bm}
// -> fp32 acc (K-window 1024, R13-proven). B register-direct from L2 (R12 layout).
// A via 32KB LDS dbuf. ~164 total regs/wave -> HW fits 3 waves/SIMD; KS=4 grid=1024
// offers 3-4 blocks/CU (R12's KS=2 grid=512 capped occupancy at 2 blocks/CU -- the
// single variable changed here).
template <int KS>
__global__ __launch_bounds__(256, 2) void logits_kernel(
    const float* __restrict__ X, const unsigned short* __restrict__ W2,
    float* __restrict__ Lp, int T) {
  constexpr int KBS = NKB / KS;
  __shared__ __align__(16) char lds[32768];  // A[i] at i*16384: h 8K | m 8K

  const int tid = threadIdx.x;
  const int lane = tid & 63;
  const int wave = tid >> 6;
  const int wm = wave >> 1, wn = wave & 1;

  // XCD-clustered remap: contiguous d-range per XCD -> W2 z-slab (1MB) L2-resident.
  const int per_xcd = 32 * KS;
  const int dd = (blockIdx.x & 7) * per_xcd + (blockIdx.x >> 3);
  const int nx = dd & 1;
  const int q = dd >> 1;
  const int y = q & 127;
  const int z = q >> 7;
  const int bm0 = y * BM;
  const int n0 = nx * BN;
  const int kb0 = z * KBS;

  // A staging: thread -> row tid>>1, 16-float half tid&1
  const int arow = tid >> 1;
  const int akh = tid & 1;
  const float* xptr = X + (size_t)(bm0 + arow) * HD + akh * 16;
  const unsigned aw0 = swz((unsigned)(arow * 64 + akh * 32));
  const unsigned aw1 = swz((unsigned)(arow * 64 + akh * 32 + 16));

  const int akg = lane >> 4;              // k-group (8 bf16)
  const int arf = wm * 64 + (lane & 15);  // A row, + mi*16

  // B direct-load base: cg = nx*8 + wn*4 + ni
  const char* wb = (const char*)W2 + (size_t)(nx * 8 + wn * 4) * 1024 + (size_t)lane * 16;

  f32x4 acc[4][4];
#pragma unroll
  for (int mi = 0; mi < 4; ++mi)
#pragma unroll
    for (int ni = 0; ni < 4; ++ni) acc[mi][ni] = (f32x4)(0.0f);

  auto convA = [&](int ai, float4 p0, float4 p1, float4 p2, float4 p3) {
    float xv[16] = {p0.x, p0.y, p0.z, p0.w, p1.x, p1.y, p1.z, p1.w,
                    p2.x, p2.y, p2.z, p2.w, p3.x, p3.y, p3.z, p3.w};
    short8 hv0, hv1, mv0, mv1;
#pragma unroll
    for (int j = 0; j < 8; ++j) {
      unsigned short h, m;
      split2(xv[j], h, m);
      hv0[j] = (short)h; mv0[j] = (short)m;
    }
#pragma unroll
    for (int j = 0; j < 8; ++j) {
      unsigned short h, m;
      split2(xv[8 + j], h, m);
      hv1[j] = (short)h; mv1[j] = (short)m;
    }
    char* ab = &lds[ai * 16384];
    *(short8*)(&ab[aw0]) = hv0;
    *(short8*)(&ab[aw1]) = hv1;
    *(short8*)(&ab[8192 + aw0]) = mv0;
    *(short8*)(&ab[8192 + aw1]) = mv1;
  };

  float4 xn0, xn1, xn2, xn3;  // x(kb+1) regs, loaded one iteration ahead

  // ---- prologue: conv A(kb0) -> buf0; prefetch x(kb0+1) ----
  {
    const float* xp = xptr + (size_t)kb0 * BK;
    float4 p0 = *(const float4*)(xp + 0);
    float4 p1 = *(const float4*)(xp + 4);
    float4 p2 = *(const float4*)(xp + 8);
    float4 p3 = *(const float4*)(xp + 12);
    convA(0, p0, p1, p2, p3);
    const float* xq = xptr + (size_t)(kb0 + 1) * BK;
    xn0 = *(const float4*)(xq + 0);
    xn1 = *(const float4*)(xq + 4);
    xn2 = *(const float4*)(xq + 8);
    xn3 = *(const float4*)(xq + 12);
    asm volatile("s_waitcnt lgkmcnt(0)" ::: "memory");
    __builtin_amdgcn_s_barrier();
  }

  for (int kb = 0; kb < KBS; ++kb) {
    const int cur = kb & 1;
    const char* ab = &lds[cur * 16384];

    // ---- B frags: 8 direct global loads (L2-resident slab, lane-linear) ----
    const char* wkb = wb + (size_t)(kb0 + kb) * 32768;
    short8 bf[2][4];
#pragma unroll
    for (int ni = 0; ni < 4; ++ni) {
      bf[0][ni] = *(const short8*)(wkb + (size_t)ni * 1024);            // h split
      bf[1][ni] = *(const short8*)(wkb + 16384 + (size_t)ni * 1024);    // m split
    }

    // ---- A frags from LDS[cur]: 8 ds_read_b128 ----
    short8 af[2][4];
#pragma unroll
    for (int mi = 0; mi < 4; ++mi) {
      unsigned rb = swz((unsigned)((arf + mi * 16) * 64 + akg * 16));
      af[0][mi] = *(const short8*)(&ab[rb]);
      af[1][mi] = *(const short8*)(&ab[8192 + rb]);
    }

    // ---- conv A(kb+1) -> LDS[nxt] (x is one-iter-old: ~0 vmem stall) ----
    if (kb + 1 < KBS) convA(cur ^ 1, xn0, xn1, xn2, xn3);

    // ---- issue x(kb+2) ----
    if (kb + 2 < KBS) {
      const float* xp = xptr + (size_t)(kb0 + kb + 2) * BK;
      xn0 = *(const float4*)(xp + 0);
      xn1 = *(const float4*)(xp + 4);
      xn2 = *(const float4*)(xp + 8);
      xn3 = *(const float4*)(xp + 12);
    }

    // ---- 64 MFMA, term-major (16 independent accs between dependent reuses) ----
    __builtin_amdgcn_s_setprio(1);
#pragma unroll
    for (int mi = 0; mi < 4; ++mi)
#pragma unroll
      for (int ni = 0; ni < 4; ++ni)
        acc[mi][ni] = MFMA(af[0][mi], bf[0][ni], acc[mi][ni], 0, 0, 0);
#pragma unroll
    for (int mi = 0; mi < 4; ++mi)
#pragma unroll
      for (int ni = 0; ni < 4; ++ni)
        acc[mi][ni] = MFMA(af[0][mi], bf[1][ni], acc[mi][ni], 0, 0, 0);
#pragma unroll
    for (int mi = 0; mi < 4; ++mi)
#pragma unroll
      for (int ni = 0; ni < 4; ++ni)
        acc[mi][ni] = MFMA(af[1][mi], bf[0][ni], acc[mi][ni], 0, 0, 0);
#pragma unroll
    for (int mi = 0; mi < 4; ++mi)
#pragma unroll
      for (int ni = 0; ni < 4; ++ni)
        acc[mi][ni] = MFMA(af[1][mi], bf[1][ni], acc[mi][ni], 0, 0, 0);
    __builtin_amdgcn_s_setprio(0);

    // ---- single barrier per kb: A[nxt] writes drained, A[cur] reads done ----
    asm volatile("s_waitcnt lgkmcnt(0)" ::: "memory");
    __builtin_amdgcn_s_barrier();
    __builtin_amdgcn_sched_barrier(0);
  }

  // ---- epilogue: C/D col=lane&15, row=(lane>>4)*4+q ----
  float* outp = Lp + (size_t)z * ((size_t)T * NE);
#pragma unroll
  for (int mi = 0; mi < 4; ++mi)
#pragma unroll
    for (int ni = 0; ni < 4; ++ni) {
      int rowbase = bm0 + wm * 64 + mi * 16 + (lane >> 4) * 4;
      int col = n0 + wn * 64 + ni * 16 + (lane & 15);
#pragma unroll
      for (int qq = 0; qq < 4; ++qq)
        outp[(size_t)(rowbase + qq) * NE + col] = acc[mi][ni][qq];
    }
}

// ---------------- gating: one wave per token, zero barriers (R6-proven) ----------------
__global__ __launch_bounds__(256) void topk_kernel(
    const float* __restrict__ Lp, const float* __restrict__ bias,
    float* __restrict__ out, int T, int ks) {
  const int lane = threadIdx.x & 63;
  const int t = blockIdx.x * 4 + (threadIdx.x >> 6);

  float4 bv = *(const float4*)(bias + lane * 4);
  double ba[4] = {bv.x, bv.y, bv.z, bv.w};

  double a0 = 0, a1 = 0, a2 = 0, a3 = 0;
  for (int zz = 0; zz < ks; ++zz) {
    float4 lv = *(const float4*)(Lp + (size_t)zz * T * NE + (size_t)t * NE + lane * 4);
    a0 += lv.x; a1 += lv.y; a2 += lv.z; a3 += lv.w;
  }
  double s[4] = {1.0 / (1.0 + exp(-a0)), 1.0 / (1.0 + exp(-a1)),
                 1.0 / (1.0 + exp(-a2)), 1.0 / (1.0 + exp(-a3))};
  double sc[4];
#pragma unroll
  for (int j = 0; j < 4; ++j) sc[j] = s[j] + ba[j];

  // group top-2 (group = 8 lanes = 32 experts)
  double m1 = sc[0], m2 = -1e300;
#pragma unroll
  for (int j = 1; j < 4; ++j) {
    if (sc[j] > m1) { m2 = m1; m1 = sc[j]; }
    else m2 = fmax(m2, sc[j]);
  }
#pragma unroll
  for (int off = 1; off <= 4; off <<= 1) {
    double o1 = __shfl_xor(m1, off);
    double o2 = __shfl_xor(m2, off);
    if (o1 > m1) { m2 = fmax(m1, o2); m1 = o1; }
    else m2 = fmax(m2, o1);
  }
  double gs = m1 + m2;

  double g[8];
#pragma unroll
  for (int gg = 0; gg < 8; ++gg) g[gg] = __shfl(gs, gg * 8);
  unsigned chosen = 0;
#pragma unroll
  for (int c = 0; c < TOPKG; ++c) {
    double best = -1e300; int bi = 0;
#pragma unroll
    for (int gg = 0; gg < 8; ++gg)
      if (!((chosen >> gg) & 1) && g[gg] > best) { best = g[gg]; bi = gg; }
    chosen |= 1u << bi;
  }
  const bool gsel = (chosen >> (lane >> 3)) & 1;

  double cand[4];
#pragma unroll
  for (int j = 0; j < 4; ++j) cand[j] = gsel ? sc[j] : -1e300;

  double wsel[TOPK]; int isel[TOPK];
  double denom = 1e-20;
#pragma unroll
  for (int it = 0; it < TOPK; ++it) {
    double v = cand[0]; int ji = 0;
#pragma unroll
    for (int j = 1; j < 4; ++j)
      if (cand[j] > v) { v = cand[j]; ji = j; }
    int idx = lane * 4 + ji;
#pragma unroll
    for (int off = 1; off <= 32; off <<= 1) {
      double ov = __shfl_xor(v, off);
      int oi = __shfl_xor(idx, off);
      if (ov > v || (ov == v && oi < idx)) { v = ov; idx = oi; }
    }
    int slot = idx & 3, owner = idx >> 2;
    double scand = s[0];
#pragma unroll
    for (int j = 1; j < 4; ++j) scand = (slot == j) ? s[j] : scand;
    double sval = __shfl(scand, owner);
    isel[it] = idx; wsel[it] = sval; denom += sval;
#pragma unroll
    for (int j = 0; j < 4; ++j)
      if (lane == owner && j == slot) cand[j] = -1e301;
  }

#pragma unroll
  for (int it = 0; it < TOPK; ++it)
    if (lane == it) {
      out[(size_t)t * TOPK + it] = (float)isel[it];
      out[(size_t)T * TOPK + (size_t)t * TOPK + it] =
          (float)(wsel[it] / denom * 2.5);
    }
}

extern "C" void kernel_launch(void* const* d_in, const int* in_sizes, int n_in,
                              void* d_out, int out_size, void* d_ws, size_t ws_size,
                              hipStream_t stream) {
  const float* X = (const float*)d_in[0];
  const float* W = (const float*)d_in[1];
  const float* bias = (const float*)d_in[2];
  float* out = (float*)d_out;
  int T = in_sizes[0] / HD;  // 16384

  unsigned short* W2 = (unsigned short*)d_ws;               // 4 MB
  const size_t w2b = (size_t)NKB * 32768;
  float* Lp = (float*)((char*)d_ws + w2b);

  const size_t need4 = w2b + 4ull * T * NE * 4;             // 4 MB + 64 MB
  const int ks = (ws_size >= need4) ? 4 : 2;

  wsplit_kernel<<<2 * NKB, 256, 0, stream>>>(W, W2);
  if (ks == 4)
    logits_kernel<4><<<256 * 4, 256, 0, stream>>>(X, W2, Lp, T);
  else
    logits_kernel<2><<<256 * 2, 256, 0, stream>>>(X, W2, Lp, T);
  topk_kernel<<<T / 4, 256, 0, stream>>>(Lp, bias, out, T, ks);
}

// Round 15
// 163.743 us; speedup vs baseline: 1.1375x; 1.1375x over previous
//
#include <hip/hip_runtime.h>
#include <math.h>

#define NE 256
#define HD 4096
#define TOPKG 4
#define TOPK 8

#define BM 128
#define BK 32
#define NKB 128  // kb across full K

typedef __attribute__((ext_vector_type(8))) short short8;
typedef __attribute__((ext_vector_type(4))) float f32x4;

typedef __attribute__((address_space(1))) const void av1_void;
typedef __attribute__((address_space(3))) void av3_void;

__device__ __forceinline__ void g2l16(const void* g, void* l) {
  __builtin_amdgcn_global_load_lds((av1_void*)g, (av3_void*)l, 16, 0, 0);
}

#define MFMA __builtin_amdgcn_mfma_f32_16x16x32_bf16

// In-row XOR swizzle (involution): byte bits[5:4] ^= addr bits[8:7].
// Verified conflict-free (R3-R14: SQ_LDS_BANK_CONFLICT == 0).
__device__ __forceinline__ unsigned swz(unsigned a) {
  return a ^ (((a >> 7) & 3u) << 4);
}

// Round-to-nearest-even bf16.
__device__ __forceinline__ unsigned short rneb(float x) {
  unsigned u = __float_as_uint(x);
  return (unsigned short)((u + 0x7fffu + ((u >> 16) & 1u)) >> 16);
}
// 2-way ROUNDED split: x = h + m + rho, |rho| <~ 2^-18|x| (R8-R14-proven numerics).
__device__ __forceinline__ void split2(float x, unsigned short& h, unsigned short& m) {
  h = rneb(x);
  float r = x - __uint_as_float(((unsigned)h) << 16);  // exact
  m = rneb(r);
}

// ---------------- W[e][k] -> packed rounded splits [kb][2][e 256][k 32] bf16 ----------------
__global__ void wsplit_kernel(const float* __restrict__ W, unsigned short* __restrict__ W2) {
  const int kb = blockIdx.x >> 1;
  const int e = (blockIdx.x & 1) * 128 + (threadIdx.x >> 1);
  const int seg = (threadIdx.x & 1) * 16;
  const float* src = W + (size_t)e * HD + kb * BK + seg;
  float4 x0 = *(const float4*)(src + 0);
  float4 x1 = *(const float4*)(src + 4);
  float4 x2 = *(const float4*)(src + 8);
  float4 x3 = *(const float4*)(src + 12);
  float xv[16] = {x0.x, x0.y, x0.z, x0.w, x1.x, x1.y, x1.z, x1.w,
                  x2.x, x2.y, x2.z, x2.w, x3.x, x3.y, x3.z, x3.w};
  short8 hv0, hv1, mv0, mv1;
#pragma unroll
  for (int j = 0; j < 8; ++j) {
    unsigned short h, m;
    split2(xv[j], h, m);
    hv0[j] = (short)h; mv0[j] = (short)m;
  }
#pragma unroll
  for (int j = 0; j < 8; ++j) {
    unsigned short h, m;
    split2(xv[8 + j], h, m);
    hv1[j] = (short)h; mv1[j] = (short)m;
  }
  unsigned short* dh = W2 + (size_t)kb * 16384 + (size_t)e * 32 + seg;  // h split
  unsigned short* dm = dh + 8192;                                       // m split
  *(short8*)(dh + 0) = hv0;
  *(short8*)(dh + 8) = hv1;
  *(short8*)(dm + 0) = mv0;
  *(short8*)(dm + 8) = mv1;
}

// ---------------- split-K logits: 128 tokens x 256 experts per block (R9 exact) ----------------
// 256 thr = 4 waves (2m x 2n), wave tile 64x128 -> 128 MFMA/wave/kb. Single-buffer
// A(16K)+B(32K) = 48KB -> 2 independent blocks/CU (phase-staggered overlap).
// 4 chains {ah,am}x{bh,bm}, one fp32 acc (K-window 1024, proven absmax 0.00195).
// Best measured config of the session: logits 152.9 us, total 163.9 (R9).
// Delta vs R9: s_setprio REMOVED (m190: setprio hurts lockstep barrier-synced GEMM).
template <int KS>
__global__ __launch_bounds__(256, 2) void logits_kernel(
    const float* __restrict__ X, const unsigned short* __restrict__ W2,
    float* __restrict__ Lp, int T) {
  constexpr int KBS = NKB / KS;
  __shared__ __align__(16) char lds[49152];  // Ah 8K | Am 8K | Bh 16K | Bm 16K

  const int tid = threadIdx.x;
  const int lane = tid & 63;
  const int wave = tid >> 6;
  const int wm = wave >> 1, wn = wave & 1;

  // z-clustered XCD remap: contiguous d-range per XCD -> W2 slab L2-resident
  const int per_xcd = 16 * KS;
  const int d = (blockIdx.x & 7) * per_xcd + (blockIdx.x >> 3);
  const int z = d >> 7;
  const int y = d & 127;
  const int bm0 = y * BM;
  const int kb0 = z * KBS;

  // A staging: thread -> row tid>>1, 16-float half tid&1
  const int arow = tid >> 1;
  const int akh = tid & 1;
  const float* xptr = X + (size_t)(bm0 + arow) * HD + akh * 16;
  const unsigned aw0 = swz((unsigned)(arow * 64 + akh * 32));
  const unsigned aw1 = swz((unsigned)(arow * 64 + akh * 32 + 16));

  const int akg = lane >> 4;               // k-group (16B)
  const int arf = wm * 64 + (lane & 15);   // A row, + mi*16
  const int bcf = wn * 128 + (lane & 15);  // B col, + ni*16

  f32x4 acc[4][8];
#pragma unroll
  for (int mi = 0; mi < 4; ++mi)
#pragma unroll
    for (int ni = 0; ni < 8; ++ni) acc[mi][ni] = (f32x4)(0.0f);

  const char* wbase = (const char*)W2;

  // B staging: 32KB slab (h 16K | m 16K), 8 rounds of 256thr x 16B.
  // Linear dest, source pre-swizzled (involution).
  auto stageB = [&](int kbg) {
    const char* slab = wbase + (size_t)kbg * 32768;
#pragma unroll
    for (int r = 0; r < 8; ++r) {
      unsigned dl = (unsigned)(r * 4096 + tid * 16);
      g2l16(slab + swz(dl), &lds[16384 + dl]);
    }
  };

  auto convA = [&](const float* xv) {
    short8 hv0, hv1, mv0, mv1;
#pragma unroll
    for (int q = 0; q < 8; ++q) {
      unsigned short h, m;
      split2(xv[q], h, m);
      hv0[q] = (short)h; mv0[q] = (short)m;
    }
#pragma unroll
    for (int q = 0; q < 8; ++q) {
      unsigned short h, m;
      split2(xv[8 + q], h, m);
      hv1[q] = (short)h; mv1[q] = (short)m;
    }
    *(short8*)(&lds[aw0]) = hv0;
    *(short8*)(&lds[aw1]) = hv1;
    *(short8*)(&lds[8192 + aw0]) = mv0;
    *(short8*)(&lds[8192 + aw1]) = mv1;
  };

  // ---- prologue ----
  {
    const float* xp = xptr + (size_t)kb0 * BK;
    float4 x0 = *(const float4*)(xp + 0);
    float4 x1 = *(const float4*)(xp + 4);
    float4 x2 = *(const float4*)(xp + 8);
    float4 x3 = *(const float4*)(xp + 12);
    stageB(kb0);
    float xv[16] = {x0.x, x0.y, x0.z, x0.w, x1.x, x1.y, x1.z, x1.w,
                    x2.x, x2.y, x2.z, x2.w, x3.x, x3.y, x3.z, x3.w};
    convA(xv);
  }
  __syncthreads();

  for (int kb = 0; kb < KBS; ++kb) {
    const bool more = (kb + 1 < KBS);

    // A frags: 4 mi x 2 splits
    short8 af[2][4];
#pragma unroll
    for (int mi = 0; mi < 4; ++mi) {
      unsigned rb = swz((unsigned)((arf + mi * 16) * 64 + akg * 16));
      af[0][mi] = *(const short8*)(&lds[rb]);
      af[1][mi] = *(const short8*)(&lds[8192 + rb]);
    }

    // x prefetch for kb+1
    float4 x0, x1, x2, x3;
    if (more) {
      const float* xp = xptr + (size_t)(kb0 + kb + 1) * BK;
      x0 = *(const float4*)(xp + 0);
      x1 = *(const float4*)(xp + 4);
      x2 = *(const float4*)(xp + 8);
      x3 = *(const float4*)(xp + 12);
    }

#pragma unroll
    for (int ni = 0; ni < 8; ++ni) {
      unsigned cb = swz((unsigned)((bcf + ni * 16) * 64 + akg * 16));
      short8 bh = *(const short8*)(&lds[16384 + cb]);
      short8 bm_ = *(const short8*)(&lds[32768 + cb]);
      // 4 chains x 4 mi; term-major (independent accs between reuses)
#pragma unroll
      for (int mi = 0; mi < 4; ++mi) acc[mi][ni] = MFMA(af[0][mi], bh,  acc[mi][ni], 0, 0, 0);
#pragma unroll
      for (int mi = 0; mi < 4; ++mi) acc[mi][ni] = MFMA(af[0][mi], bm_, acc[mi][ni], 0, 0, 0);
#pragma unroll
      for (int mi = 0; mi < 4; ++mi) acc[mi][ni] = MFMA(af[1][mi], bh,  acc[mi][ni], 0, 0, 0);
#pragma unroll
      for (int mi = 0; mi < 4; ++mi) acc[mi][ni] = MFMA(af[1][mi], bm_, acc[mi][ni], 0, 0, 0);
    }

    __syncthreads();  // all waves done reading LDS

    if (more) {
      stageB(kb0 + kb + 1);  // overwrite B (safe after barrier)
      float xv[16] = {x0.x, x0.y, x0.z, x0.w, x1.x, x1.y, x1.z, x1.w,
                      x2.x, x2.y, x2.z, x2.w, x3.x, x3.y, x3.z, x3.w};
      convA(xv);             // overwrite A; waits x only (FIFO vmcnt)
      __syncthreads();       // staging visible + g2l16 drained (other block covers stall)
    }
  }

  // ---- epilogue: C/D col=lane&15, row=(lane>>4)*4+q ----
  float* outp = Lp + (size_t)z * ((size_t)T * NE);
#pragma unroll
  for (int mi = 0; mi < 4; ++mi)
#pragma unroll
    for (int ni = 0; ni < 8; ++ni) {
      int rowbase = bm0 + wm * 64 + mi * 16 + (lane >> 4) * 4;
      int col = wn * 128 + ni * 16 + (lane & 15);
#pragma unroll
      for (int q = 0; q < 4; ++q)
        outp[(size_t)(rowbase + q) * NE + col] = acc[mi][ni][q];
    }
}

// ---------------- gating: one wave per token, zero barriers (R6-proven) ----------------
__global__ __launch_bounds__(256) void topk_kernel(
    const float* __restrict__ Lp, const float* __restrict__ bias,
    float* __restrict__ out, int T, int ks) {
  const int lane = threadIdx.x & 63;
  const int t = blockIdx.x * 4 + (threadIdx.x >> 6);

  float4 bv = *(const float4*)(bias + lane * 4);
  double ba[4] = {bv.x, bv.y, bv.z, bv.w};

  double a0 = 0, a1 = 0, a2 = 0, a3 = 0;
  for (int zz = 0; zz < ks; ++zz) {
    float4 lv = *(const float4*)(Lp + (size_t)zz * T * NE + (size_t)t * NE + lane * 4);
    a0 += lv.x; a1 += lv.y; a2 += lv.z; a3 += lv.w;
  }
  double s[4] = {1.0 / (1.0 + exp(-a0)), 1.0 / (1.0 + exp(-a1)),
                 1.0 / (1.0 + exp(-a2)), 1.0 / (1.0 + exp(-a3))};
  double sc[4];
#pragma unroll
  for (int j = 0; j < 4; ++j) sc[j] = s[j] + ba[j];

  // group top-2 (group = 8 lanes = 32 experts)
  double m1 = sc[0], m2 = -1e300;
#pragma unroll
  for (int j = 1; j < 4; ++j) {
    if (sc[j] > m1) { m2 = m1; m1 = sc[j]; }
    else m2 = fmax(m2, sc[j]);
  }
#pragma unroll
  for (int off = 1; off <= 4; off <<= 1) {
    double o1 = __shfl_xor(m1, off);
    double o2 = __shfl_xor(m2, off);
    if (o1 > m1) { m2 = fmax(m1, o2); m1 = o1; }
    else m2 = fmax(m2, o1);
  }
  double gs = m1 + m2;

  double g[8];
#pragma unroll
  for (int gg = 0; gg < 8; ++gg) g[gg] = __shfl(gs, gg * 8);
  unsigned chosen = 0;
#pragma unroll
  for (int c = 0; c < TOPKG; ++c) {
    double best = -1e300; int bi = 0;
#pragma unroll
    for (int gg = 0; gg < 8; ++gg)
      if (!((chosen >> gg) & 1) && g[gg] > best) { best = g[gg]; bi = gg; }
    chosen |= 1u << bi;
  }
  const bool gsel = (chosen >> (lane >> 3)) & 1;

  double cand[4];
#pragma unroll
  for (int j = 0; j < 4; ++j) cand[j] = gsel ? sc[j] : -1e300;

  double wsel[TOPK]; int isel[TOPK];
  double denom = 1e-20;
#pragma unroll
  for (int it = 0; it < TOPK; ++it) {
    double v = cand[0]; int ji = 0;
#pragma unroll
    for (int j = 1; j < 4; ++j)
      if (cand[j] > v) { v = cand[j]; ji = j; }
    int idx = lane * 4 + ji;
#pragma unroll
    for (int off = 1; off <= 32; off <<= 1) {
      double ov = __shfl_xor(v, off);
      int oi = __shfl_xor(idx, off);
      if (ov > v || (ov == v && oi < idx)) { v = ov; idx = oi; }
    }
    int slot = idx & 3, owner = idx >> 2;
    double scand = s[0];
#pragma unroll
    for (int j = 1; j < 4; ++j) scand = (slot == j) ? s[j] : scand;
    double sval = __shfl(scand, owner);
    isel[it] = idx; wsel[it] = sval; denom += sval;
#pragma unroll
    for (int j = 0; j < 4; ++j)
      if (lane == owner && j == slot) cand[j] = -1e301;
  }

#pragma unroll
  for (int it = 0; it < TOPK; ++it)
    if (lane == it) {
      out[(size_t)t * TOPK + it] = (float)isel[it];
      out[(size_t)T * TOPK + (size_t)t * TOPK + it] =
          (float)(wsel[it] / denom * 2.5);
    }
}

extern "C" void kernel_launch(void* const* d_in, const int* in_sizes, int n_in,
                              void* d_out, int out_size, void* d_ws, size_t ws_size,
                              hipStream_t stream) {
  const float* X = (const float*)d_in[0];
  const float* W = (const float*)d_in[1];
  const float* bias = (const float*)d_in[2];
  float* out = (float*)d_out;
  int T = in_sizes[0] / HD;  // 16384

  unsigned short* W2 = (unsigned short*)d_ws;               // 4 MB
  const size_t w2b = (size_t)NKB * 32768;
  float* Lp = (float*)((char*)d_ws + w2b);

  const size_t need4 = w2b + 4ull * T * NE * 4;             // 4 MB + 64 MB
  const int ks = (ws_size >= need4) ? 4 : 2;

  wsplit_kernel<<<2 * NKB, 256, 0, stream>>>(W, W2);
  if (ks == 4)
    logits_kernel<4><<<128 * 4, 256, 0, stream>>>(X, W2, Lp, T);
  else
    logits_kernel<2><<<128 * 2, 256, 0, stream>>>(X, W2, Lp, T);
  topk_kernel<<<T / 4, 256, 0, stream>>>(Lp, bias, out, T, ks);
}

// Round 17
// 161.821 us; speedup vs baseline: 1.1510x; 1.0119x over previous
//
#include <hip/hip_runtime.h>
#include <math.h>

#define NE 256
#define HD 4096
#define TOPKG 4
#define TOPK 8

#define BM 128
#define BK 32
#define NKB 128  // kb across full K

typedef __attribute__((ext_vector_type(8))) short short8;
typedef __attribute__((ext_vector_type(4))) float f32x4;

typedef __attribute__((address_space(1))) const void av1_void;
typedef __attribute__((address_space(3))) void av3_void;

__device__ __forceinline__ void g2l16(const void* g, void* l) {
  __builtin_amdgcn_global_load_lds((av1_void*)g, (av3_void*)l, 16, 0, 0);
}

#define MFMA __builtin_amdgcn_mfma_f32_16x16x32_bf16

// In-row XOR swizzle (involution): byte bits[5:4] ^= addr bits[8:7].
// Verified conflict-free (R3-R15: SQ_LDS_BANK_CONFLICT == 0).
__device__ __forceinline__ unsigned swz(unsigned a) {
  return a ^ (((a >> 7) & 3u) << 4);
}

// Round-to-nearest-even bf16.
__device__ __forceinline__ unsigned short rneb(float x) {
  unsigned u = __float_as_uint(x);
  return (unsigned short)((u + 0x7fffu + ((u >> 16) & 1u)) >> 16);
}
// 2-way ROUNDED split: x = h + m + rho, |rho| <~ 2^-18|x|.
// R16 falsification: ALL FOUR chains {ah,am}x{bh,bm} are required — dropping
// am*bm flips top-8 indices (absmax 74). 4 chains = verified minimum math.
__device__ __forceinline__ void split2(float x, unsigned short& h, unsigned short& m) {
  h = rneb(x);
  float r = x - __uint_as_float(((unsigned)h) << 16);  // exact
  m = rneb(r);
}

// ---------------- W[e][k] -> packed rounded splits [kb][2][e 256][k 32] bf16 ----------------
__global__ void wsplit_kernel(const float* __restrict__ W, unsigned short* __restrict__ W2) {
  const int kb = blockIdx.x >> 1;
  const int e = (blockIdx.x & 1) * 128 + (threadIdx.x >> 1);
  const int seg = (threadIdx.x & 1) * 16;
  const float* src = W + (size_t)e * HD + kb * BK + seg;
  float4 x0 = *(const float4*)(src + 0);
  float4 x1 = *(const float4*)(src + 4);
  float4 x2 = *(const float4*)(src + 8);
  float4 x3 = *(const float4*)(src + 12);
  float xv[16] = {x0.x, x0.y, x0.z, x0.w, x1.x, x1.y, x1.z, x1.w,
                  x2.x, x2.y, x2.z, x2.w, x3.x, x3.y, x3.z, x3.w};
  short8 hv0, hv1, mv0, mv1;
#pragma unroll
  for (int j = 0; j < 8; ++j) {
    unsigned short h, m;
    split2(xv[j], h, m);
    hv0[j] = (short)h; mv0[j] = (short)m;
  }
#pragma unroll
  for (int j = 0; j < 8; ++j) {
    unsigned short h, m;
    split2(xv[8 + j], h, m);
    hv1[j] = (short)h; mv1[j] = (short)m;
  }
  unsigned short* dh = W2 + (size_t)kb * 16384 + (size_t)e * 32 + seg;  // h split
  unsigned short* dm = dh + 8192;                                       // m split
  *(short8*)(dh + 0) = hv0;
  *(short8*)(dh + 8) = hv1;
  *(short8*)(dm + 0) = mv0;
  *(short8*)(dm + 8) = mv1;
}

// ---------------- split-K logits: 128 tokens x 256 experts per block (R9/R15 best) ----------------
// 256 thr = 4 waves (2m x 2n), wave tile 64x128 -> 128 MFMA/wave/kb. Single-buffer
// A(16K)+B(32K) = 48KB -> 2 independent blocks/CU (phase-staggered overlap).
// 4 chains {ah,am}x{bh,bm}, one fp32 acc (K-window 1024, absmax 0.00195 verified).
// Best measured config of the session: logits ~153 us, total ~163.8 us.
// Plateau confirmed across 7 schedule axes (R9-R15) + work axis (R16 failed);
// ~900 TF effective is this structure's practical ceiling on gfx950.
template <int KS>
__global__ __launch_bounds__(256, 2) void logits_kernel(
    const float* __restrict__ X, const unsigned short* __restrict__ W2,
    float* __restrict__ Lp, int T) {
  constexpr int KBS = NKB / KS;
  __shared__ __align__(16) char lds[49152];  // Ah 8K | Am 8K | Bh 16K | Bm 16K

  const int tid = threadIdx.x;
  const int lane = tid & 63;
  const int wave = tid >> 6;
  const int wm = wave >> 1, wn = wave & 1;

  // z-clustered XCD remap: contiguous d-range per XCD -> W2 slab L2-resident
  const int per_xcd = 16 * KS;
  const int d = (blockIdx.x & 7) * per_xcd + (blockIdx.x >> 3);
  const int z = d >> 7;
  const int y = d & 127;
  const int bm0 = y * BM;
  const int kb0 = z * KBS;

  // A staging: thread -> row tid>>1, 16-float half tid&1
  const int arow = tid >> 1;
  const int akh = tid & 1;
  const float* xptr = X + (size_t)(bm0 + arow) * HD + akh * 16;
  const unsigned aw0 = swz((unsigned)(arow * 64 + akh * 32));
  const unsigned aw1 = swz((unsigned)(arow * 64 + akh * 32 + 16));

  const int akg = lane >> 4;               // k-group (16B)
  const int arf = wm * 64 + (lane & 15);   // A row, + mi*16
  const int bcf = wn * 128 + (lane & 15);  // B col, + ni*16

  f32x4 acc[4][8];
#pragma unroll
  for (int mi = 0; mi < 4; ++mi)
#pragma unroll
    for (int ni = 0; ni < 8; ++ni) acc[mi][ni] = (f32x4)(0.0f);

  const char* wbase = (const char*)W2;

  // B staging: 32KB slab (h 16K | m 16K), 8 rounds of 256thr x 16B.
  // Linear dest, source pre-swizzled (involution).
  auto stageB = [&](int kbg) {
    const char* slab = wbase + (size_t)kbg * 32768;
#pragma unroll
    for (int r = 0; r < 8; ++r) {
      unsigned dl = (unsigned)(r * 4096 + tid * 16);
      g2l16(slab + swz(dl), &lds[16384 + dl]);
    }
  };

  auto convA = [&](const float* xv) {
    short8 hv0, hv1, mv0, mv1;
#pragma unroll
    for (int q = 0; q < 8; ++q) {
      unsigned short h, m;
      split2(xv[q], h, m);
      hv0[q] = (short)h; mv0[q] = (short)m;
    }
#pragma unroll
    for (int q = 0; q < 8; ++q) {
      unsigned short h, m;
      split2(xv[8 + q], h, m);
      hv1[q] = (short)h; mv1[q] = (short)m;
    }
    *(short8*)(&lds[aw0]) = hv0;
    *(short8*)(&lds[aw1]) = hv1;
    *(short8*)(&lds[8192 + aw0]) = mv0;
    *(short8*)(&lds[8192 + aw1]) = mv1;
  };

  // ---- prologue ----
  {
    const float* xp = xptr + (size_t)kb0 * BK;
    float4 x0 = *(const float4*)(xp + 0);
    float4 x1 = *(const float4*)(xp + 4);
    float4 x2 = *(const float4*)(xp + 8);
    float4 x3 = *(const float4*)(xp + 12);
    stageB(kb0);
    float xv[16] = {x0.x, x0.y, x0.z, x0.w, x1.x, x1.y, x1.z, x1.w,
                    x2.x, x2.y, x2.z, x2.w, x3.x, x3.y, x3.z, x3.w};
    convA(xv);
  }
  __syncthreads();

  for (int kb = 0; kb < KBS; ++kb) {
    const bool more = (kb + 1 < KBS);

    // A frags: 4 mi x 2 splits
    short8 af[2][4];
#pragma unroll
    for (int mi = 0; mi < 4; ++mi) {
      unsigned rb = swz((unsigned)((arf + mi * 16) * 64 + akg * 16));
      af[0][mi] = *(const short8*)(&lds[rb]);
      af[1][mi] = *(const short8*)(&lds[8192 + rb]);
    }

    // x prefetch for kb+1
    float4 x0, x1, x2, x3;
    if (more) {
      const float* xp = xptr + (size_t)(kb0 + kb + 1) * BK;
      x0 = *(const float4*)(xp + 0);
      x1 = *(const float4*)(xp + 4);
      x2 = *(const float4*)(xp + 8);
      x3 = *(const float4*)(xp + 12);
    }

#pragma unroll
    for (int ni = 0; ni < 8; ++ni) {
      unsigned cb = swz((unsigned)((bcf + ni * 16) * 64 + akg * 16));
      short8 bh = *(const short8*)(&lds[16384 + cb]);
      short8 bm_ = *(const short8*)(&lds[32768 + cb]);
      // 4 chains x 4 mi; term-major (independent accs between reuses)
#pragma unroll
      for (int mi = 0; mi < 4; ++mi) acc[mi][ni] = MFMA(af[0][mi], bh,  acc[mi][ni], 0, 0, 0);
#pragma unroll
      for (int mi = 0; mi < 4; ++mi) acc[mi][ni] = MFMA(af[0][mi], bm_, acc[mi][ni], 0, 0, 0);
#pragma unroll
      for (int mi = 0; mi < 4; ++mi) acc[mi][ni] = MFMA(af[1][mi], bh,  acc[mi][ni], 0, 0, 0);
#pragma unroll
      for (int mi = 0; mi < 4; ++mi) acc[mi][ni] = MFMA(af[1][mi], bm_, acc[mi][ni], 0, 0, 0);
    }

    __syncthreads();  // all waves done reading LDS

    if (more) {
      stageB(kb0 + kb + 1);  // overwrite B (safe after barrier)
      float xv[16] = {x0.x, x0.y, x0.z, x0.w, x1.x, x1.y, x1.z, x1.w,
                      x2.x, x2.y, x2.z, x2.w, x3.x, x3.y, x3.z, x3.w};
      convA(xv);             // overwrite A; waits x only (FIFO vmcnt)
      __syncthreads();       // staging visible + g2l16 drained (other block covers stall)
    }
  }

  // ---- epilogue: C/D col=lane&15, row=(lane>>4)*4+q ----
  float* outp = Lp + (size_t)z * ((size_t)T * NE);
#pragma unroll
  for (int mi = 0; mi < 4; ++mi)
#pragma unroll
    for (int ni = 0; ni < 8; ++ni) {
      int rowbase = bm0 + wm * 64 + mi * 16 + (lane >> 4) * 4;
      int col = wn * 128 + ni * 16 + (lane & 15);
#pragma unroll
      for (int q = 0; q < 4; ++q)
        outp[(size_t)(rowbase + q) * NE + col] = acc[mi][ni][q];
    }
}

// ---------------- gating: one wave per token, zero barriers (R6-proven) ----------------
__global__ __launch_bounds__(256) void topk_kernel(
    const float* __restrict__ Lp, const float* __restrict__ bias,
    float* __restrict__ out, int T, int ks) {
  const int lane = threadIdx.x & 63;
  const int t = blockIdx.x * 4 + (threadIdx.x >> 6);

  float4 bv = *(const float4*)(bias + lane * 4);
  double ba[4] = {bv.x, bv.y, bv.z, bv.w};

  double a0 = 0, a1 = 0, a2 = 0, a3 = 0;
  for (int zz = 0; zz < ks; ++zz) {
    float4 lv = *(const float4*)(Lp + (size_t)zz * T * NE + (size_t)t * NE + lane * 4);
    a0 += lv.x; a1 += lv.y; a2 += lv.z; a3 += lv.w;
  }
  double s[4] = {1.0 / (1.0 + exp(-a0)), 1.0 / (1.0 + exp(-a1)),
                 1.0 / (1.0 + exp(-a2)), 1.0 / (1.0 + exp(-a3))};
  double sc[4];
#pragma unroll
  for (int j = 0; j < 4; ++j) sc[j] = s[j] + ba[j];

  // group top-2 (group = 8 lanes = 32 experts)
  double m1 = sc[0], m2 = -1e300;
#pragma unroll
  for (int j = 1; j < 4; ++j) {
    if (sc[j] > m1) { m2 = m1; m1 = sc[j]; }
    else m2 = fmax(m2, sc[j]);
  }
#pragma unroll
  for (int off = 1; off <= 4; off <<= 1) {
    double o1 = __shfl_xor(m1, off);
    double o2 = __shfl_xor(m2, off);
    if (o1 > m1) { m2 = fmax(m1, o2); m1 = o1; }
    else m2 = fmax(m2, o1);
  }
  double gs = m1 + m2;

  double g[8];
#pragma unroll
  for (int gg = 0; gg < 8; ++gg) g[gg] = __shfl(gs, gg * 8);
  unsigned chosen = 0;
#pragma unroll
  for (int c = 0; c < TOPKG; ++c) {
    double best = -1e300; int bi = 0;
#pragma unroll
    for (int gg = 0; gg < 8; ++gg)
      if (!((chosen >> gg) & 1) && g[gg] > best) { best = g[gg]; bi = gg; }
    chosen |= 1u << bi;
  }
  const bool gsel = (chosen >> (lane >> 3)) & 1;

  double cand[4];
#pragma unroll
  for (int j = 0; j < 4; ++j) cand[j] = gsel ? sc[j] : -1e300;

  double wsel[TOPK]; int isel[TOPK];
  double denom = 1e-20;
#pragma unroll
  for (int it = 0; it < TOPK; ++it) {
    double v = cand[0]; int ji = 0;
#pragma unroll
    for (int j = 1; j < 4; ++j)
      if (cand[j] > v) { v = cand[j]; ji = j; }
    int idx = lane * 4 + ji;
#pragma unroll
    for (int off = 1; off <= 32; off <<= 1) {
      double ov = __shfl_xor(v, off);
      int oi = __shfl_xor(idx, off);
      if (ov > v || (ov == v && oi < idx)) { v = ov; idx = oi; }
    }
    int slot = idx & 3, owner = idx >> 2;
    double scand = s[0];
#pragma unroll
    for (int j = 1; j < 4; ++j) scand = (slot == j) ? s[j] : scand;
    double sval = __shfl(scand, owner);
    isel[it] = idx; wsel[it] = sval; denom += sval;
#pragma unroll
    for (int j = 0; j < 4; ++j)
      if (lane == owner && j == slot) cand[j] = -1e301;
  }

#pragma unroll
  for (int it = 0; it < TOPK; ++it)
    if (lane == it) {
      out[(size_t)t * TOPK + it] = (float)isel[it];
      out[(size_t)T * TOPK + (size_t)t * TOPK + it] =
          (float)(wsel[it] / denom * 2.5);
    }
}

extern "C" void kernel_launch(void* const* d_in, const int* in_sizes, int n_in,
                              void* d_out, int out_size, void* d_ws, size_t ws_size,
                              hipStream_t stream) {
  const float* X = (const float*)d_in[0];
  const float* W = (const float*)d_in[1];
  const float* bias = (const float*)d_in[2];
  float* out = (float*)d_out;
  int T = in_sizes[0] / HD;  // 16384

  unsigned short* W2 = (unsigned short*)d_ws;               // 4 MB
  const size_t w2b = (size_t)NKB * 32768;
  float* Lp = (float*)((char*)d_ws + w2b);

  const size_t need4 = w2b + 4ull * T * NE * 4;             // 4 MB + 64 MB
  const int ks = (ws_size >= need4) ? 4 : 2;

  wsplit_kernel<<<2 * NKB, 256, 0, stream>>>(W, W2);
  if (ks == 4)
    logits_kernel<4><<<128 * 4, 256, 0, stream>>>(X, W2, Lp, T);
  else
    logits_kernel<2><<<128 * 2, 256, 0, stream>>>(X, W2, Lp, T);
  topk_kernel<<<T / 4, 256, 0, stream>>>(Lp, bias, out, T, ks);
}